// Round 3
// baseline (727.334 us; speedup 1.0000x reference)
//
#include <hip/hip_runtime.h>
#include <hip/hip_bf16.h>

#define T_TOK 2048
#define D_DIM 1024
#define H_DIM 2816
#define E_NUM 8

// padded LDS strides (shorts): multiple of 8 (16B-aligned rows) chosen so
// b128 fragment reads hit the 8-phase floor (bank = f(row) spreads starts)
#define BS13 1040   // K=1024 + 16
#define BS2  2824   // K=2816 + 8

typedef __attribute__((ext_vector_type(8))) short short8;
typedef __attribute__((ext_vector_type(4))) float floatx4;
typedef __attribute__((ext_vector_type(8))) unsigned short ushort8_t;

__device__ __forceinline__ unsigned short f2bf(float f) {
    unsigned int b = __float_as_uint(f);
    b += 0x7FFFu + ((b >> 16) & 1u);   // round-to-nearest-even
    return (unsigned short)(b >> 16);
}

__device__ __forceinline__ ushort8_t cvt8(float4 a, float4 b) {
    ushort8_t o;
    o[0] = f2bf(a.x); o[1] = f2bf(a.y); o[2] = f2bf(a.z); o[3] = f2bf(a.w);
    o[4] = f2bf(b.x); o[5] = f2bf(b.y); o[6] = f2bf(b.z); o[7] = f2bf(b.w);
    return o;
}

// ---------------- x -> bf16 (8 elem/thread) ----------------
__global__ __launch_bounds__(256) void k_convert(const float* __restrict__ src,
                                                 unsigned short* __restrict__ dst) {
    int i = blockIdx.x * 256 + threadIdx.x;
    float4 a = ((const float4*)src)[2 * i];
    float4 b = ((const float4*)src)[2 * i + 1];
    ((ushort8_t*)dst)[i] = cvt8(a, b);
}

// ---------------- gating: wave per token ----------------
__global__ __launch_bounds__(256) void k_gate(const float* __restrict__ x,
                                              const float* __restrict__ Wg,
                                              int* __restrict__ topi, float* __restrict__ topw,
                                              int* __restrict__ counts) {
    int wave = threadIdx.x >> 6, lane = threadIdx.x & 63;
    int t = blockIdx.x * 4 + wave;
    const float* xr = x + (size_t)t * D_DIM;
    float acc[E_NUM];
#pragma unroll
    for (int e = 0; e < E_NUM; ++e) acc[e] = 0.f;
    for (int i = 0; i < D_DIM / 64; ++i) {
        float xv = xr[lane + 64 * i];
#pragma unroll
        for (int e = 0; e < E_NUM; ++e) acc[e] += xv * Wg[e * D_DIM + lane + 64 * i];
    }
#pragma unroll
    for (int e = 0; e < E_NUM; ++e) {
#pragma unroll
        for (int s = 32; s > 0; s >>= 1) acc[e] += __shfl_xor(acc[e], s, 64);
    }
    if (lane == 0) {
        float mx = acc[0];
#pragma unroll
        for (int e = 1; e < E_NUM; ++e) mx = fmaxf(mx, acc[e]);
        float p[E_NUM], s = 0.f;
#pragma unroll
        for (int e = 0; e < E_NUM; ++e) { p[e] = expf(acc[e] - mx); s += p[e]; }
        int i0 = 0;
#pragma unroll
        for (int e = 1; e < E_NUM; ++e) if (p[e] > p[i0]) i0 = e;
        int i1 = (i0 == 0) ? 1 : 0;
#pragma unroll
        for (int e = 0; e < E_NUM; ++e) if (e != i0 && p[e] > p[i1]) i1 = e;
        float s0 = p[i0] / s, s1 = p[i1] / s;
        float d = s0 + s1 + 1e-20f;
        topi[t * 2] = i0; topi[t * 2 + 1] = i1;
        topw[t * 2] = s0 / d; topw[t * 2 + 1] = s1 / d;
        atomicAdd(&counts[i0], 1);
        atomicAdd(&counts[i1], 1);
    }
}

// ---------------- prefix scan over 8 counts ----------------
__global__ void k_scan(const int* __restrict__ counts, int* __restrict__ offs,
                       int* __restrict__ cursor) {
    if (threadIdx.x == 0) {
        int s = 0;
        for (int e = 0; e < E_NUM; ++e) { offs[e] = s; cursor[e] = s; s += counts[e]; }
        offs[E_NUM] = s;
    }
}

// ---------------- scatter tokens into per-expert lists ----------------
__global__ __launch_bounds__(256) void k_scatter(const int* __restrict__ topi,
                                                 int* __restrict__ cursor,
                                                 int* __restrict__ ltok,
                                                 int* __restrict__ tpos) {
    int t = blockIdx.x * 256 + threadIdx.x;
#pragma unroll
    for (int k = 0; k < 2; ++k) {
        int e = topi[t * 2 + k];
        int pos = atomicAdd(&cursor[e], 1);
        ltok[pos] = t;
        tpos[t * 2 + k] = pos;
    }
}

// ---- GEMM 1&3: weight-resident. Block = (ntile of 16 H-cols, expert). ----
// Full-K W1/W3 slices live in LDS (converted once); M-loop over token tiles of
// 256 rows (64/wave); K-loop has NO barriers; A read straight from global/LLC.
__global__ __launch_bounds__(256, 2) void k_gemm13(const unsigned short* __restrict__ xb,
                                                   const float* __restrict__ W1,
                                                   const float* __restrict__ W3,
                                                   const int* __restrict__ ltok,
                                                   const int* __restrict__ offs,
                                                   const int* __restrict__ counts,
                                                   unsigned short* __restrict__ U) {
    const int nt = blockIdx.x;              // 0..175
    const int e  = blockIdx.y;
    const int cnt = counts[e], off = offs[e];

    __shared__ __align__(16) unsigned short B1s[16 * BS13];
    __shared__ __align__(16) unsigned short B3s[16 * BS13];

    const int tid = threadIdx.x, lane = tid & 63, wave = tid >> 6;

    // ---- stage both weight slices: f32 -> bf16 -> LDS (once per block) ----
    {
        const int row = tid >> 4, cl = tid & 15;
        const float* w1r = W1 + ((size_t)e * H_DIM + nt * 16 + row) * D_DIM;
        const float* w3r = W3 + ((size_t)e * H_DIM + nt * 16 + row) * D_DIM;
#pragma unroll
        for (int i = 0; i < 8; ++i) {
            int col = (cl + 16 * i) * 8;
            float4 a = *(const float4*)(w1r + col);
            float4 b = *(const float4*)(w1r + col + 4);
            *(ushort8_t*)&B1s[row * BS13 + col] = cvt8(a, b);
            float4 c = *(const float4*)(w3r + col);
            float4 d = *(const float4*)(w3r + col + 4);
            *(ushort8_t*)&B3s[row * BS13 + col] = cvt8(c, d);
        }
    }
    __syncthreads();

    const int fr = lane & 15, quad = lane >> 4;

    for (int mb = 0; mb < cnt; mb += 256) {
        const int rbase = mb + wave * 64;
        const unsigned short* ap[4];
#pragma unroll
        for (int m = 0; m < 4; ++m) {
            int g = rbase + m * 16 + fr;
            if (g >= cnt) g = cnt - 1;
            int t = ltok[off + g];
            ap[m] = xb + (size_t)t * D_DIM + quad * 8;
        }
        floatx4 acc1[4], acc3[4];
#pragma unroll
        for (int m = 0; m < 4; ++m) { acc1[m] = (floatx4)0.f; acc3[m] = (floatx4)0.f; }

#pragma unroll 4
        for (int k0 = 0; k0 < D_DIM; k0 += 64) {
            short8 a[4][2];
#pragma unroll
            for (int m = 0; m < 4; ++m) {
                a[m][0] = *(const short8*)(ap[m] + k0);
                a[m][1] = *(const short8*)(ap[m] + k0 + 32);
            }
            short8 b1[2], b3[2];
#pragma unroll
            for (int kk = 0; kk < 2; ++kk) {
                b1[kk] = *(const short8*)&B1s[fr * BS13 + k0 + kk * 32 + quad * 8];
                b3[kk] = *(const short8*)&B3s[fr * BS13 + k0 + kk * 32 + quad * 8];
            }
#pragma unroll
            for (int m = 0; m < 4; ++m) {
#pragma unroll
                for (int kk = 0; kk < 2; ++kk) {
                    acc1[m] = __builtin_amdgcn_mfma_f32_16x16x32_bf16(a[m][kk], b1[kk], acc1[m], 0, 0, 0);
                    acc3[m] = __builtin_amdgcn_mfma_f32_16x16x32_bf16(a[m][kk], b3[kk], acc3[m], 0, 0, 0);
                }
            }
        }

#pragma unroll
        for (int m = 0; m < 4; ++m) {
#pragma unroll
            for (int r = 0; r < 4; ++r) {
                int g = rbase + m * 16 + quad * 4 + r;
                if (g < cnt) {
                    float u1 = acc1[m][r], u3 = acc3[m][r];
                    float u = u1 / (1.f + __expf(-u1)) * u3;
                    U[(size_t)(off + g) * H_DIM + nt * 16 + fr] = f2bf(u);
                }
            }
        }
    }
}

// ---- GEMM 2: weight-resident. Block = (ntile of 16 D-cols, expert). ----
// Writes unweighted Yp[pos][D]; combine applies gate weights (no atomics).
__global__ __launch_bounds__(256) void k_gemm2(const unsigned short* __restrict__ U,
                                               const float* __restrict__ W2,
                                               const int* __restrict__ offs,
                                               const int* __restrict__ counts,
                                               float* __restrict__ Yp) {
    const int nt = blockIdx.x;              // 0..63
    const int e  = blockIdx.y;
    const int cnt = counts[e], off = offs[e];

    __shared__ __align__(16) unsigned short Bs[16 * BS2];

    const int tid = threadIdx.x, lane = tid & 63, wave = tid >> 6;

    {
        const int row = tid >> 4, cl = tid & 15;
        const float* w2r = W2 + ((size_t)e * D_DIM + nt * 16 + row) * H_DIM;
#pragma unroll
        for (int i = 0; i < 22; ++i) {
            int col = (cl + 16 * i) * 8;
            float4 a = *(const float4*)(w2r + col);
            float4 b = *(const float4*)(w2r + col + 4);
            *(ushort8_t*)&Bs[row * BS2 + col] = cvt8(a, b);
        }
    }
    __syncthreads();

    const int fr = lane & 15, quad = lane >> 4;

    for (int mb = 0; mb < cnt; mb += 256) {
        const int rbase = mb + wave * 64;
        const unsigned short* ap[4];
#pragma unroll
        for (int m = 0; m < 4; ++m) {
            int g = rbase + m * 16 + fr;
            if (g >= cnt) g = cnt - 1;
            ap[m] = U + (size_t)(off + g) * H_DIM + quad * 8;
        }
        floatx4 acc[4];
#pragma unroll
        for (int m = 0; m < 4; ++m) acc[m] = (floatx4)0.f;

#pragma unroll 4
        for (int k0 = 0; k0 < H_DIM; k0 += 64) {
            short8 a[4][2];
#pragma unroll
            for (int m = 0; m < 4; ++m) {
                a[m][0] = *(const short8*)(ap[m] + k0);
                a[m][1] = *(const short8*)(ap[m] + k0 + 32);
            }
            short8 b[2];
#pragma unroll
            for (int kk = 0; kk < 2; ++kk)
                b[kk] = *(const short8*)&Bs[fr * BS2 + k0 + kk * 32 + quad * 8];
#pragma unroll
            for (int m = 0; m < 4; ++m) {
#pragma unroll
                for (int kk = 0; kk < 2; ++kk)
                    acc[m] = __builtin_amdgcn_mfma_f32_16x16x32_bf16(a[m][kk], b[kk], acc[m], 0, 0, 0);
            }
        }

#pragma unroll
        for (int m = 0; m < 4; ++m) {
#pragma unroll
            for (int r = 0; r < 4; ++r) {
                int g = rbase + m * 16 + quad * 4 + r;
                if (g < cnt)
                    Yp[(size_t)(off + g) * D_DIM + nt * 16 + fr] = acc[m][r];
            }
        }
    }
}

// ---- combine: y[t] = w0*Yp[p0] + w1*Yp[p1] (float4 per thread) ----
__global__ __launch_bounds__(256) void k_combine(const float* __restrict__ Yp,
                                                 const int* __restrict__ tpos,
                                                 const float* __restrict__ topw,
                                                 float* __restrict__ y) {
    int i = blockIdx.x * 256 + threadIdx.x;       // over T*D/4
    int t = i >> 8, c = i & 255;
    int p0 = tpos[t * 2], p1 = tpos[t * 2 + 1];
    float w0 = topw[t * 2], w1 = topw[t * 2 + 1];
    float4 a = ((const float4*)Yp)[(size_t)p0 * 256 + c];
    float4 b = ((const float4*)Yp)[(size_t)p1 * 256 + c];
    float4 o;
    o.x = w0 * a.x + w1 * b.x;
    o.y = w0 * a.y + w1 * b.y;
    o.z = w0 * a.z + w1 * b.z;
    o.w = w0 * a.w + w1 * b.w;
    ((float4*)y)[i] = o;
}

// ---------------- workspace layout ----------------
static const size_t OFF_XB   = 0;                         // T*D*2      =  4,194,304
static const size_t OFF_U    = 4194304;                   // 2T*H*2     = 23,068,672
static const size_t OFF_YP   = OFF_U + 23068672;          // 2T*D*4     = 16,777,216
static const size_t OFF_TOPI = OFF_YP + 16777216;         // 2T ints
static const size_t OFF_TOPW = OFF_TOPI + 16384;
static const size_t OFF_TPOS = OFF_TOPW + 16384;
static const size_t OFF_LTOK = OFF_TPOS + 16384;
static const size_t OFF_META = OFF_LTOK + 16384;          // counts[8], cursor[8], offs[9]

extern "C" void kernel_launch(void* const* d_in, const int* in_sizes, int n_in,
                              void* d_out, int out_size, void* d_ws, size_t ws_size,
                              hipStream_t stream) {
    const float* x  = (const float*)d_in[0];
    const float* Wg = (const float*)d_in[1];
    const float* W1 = (const float*)d_in[2];
    const float* W2 = (const float*)d_in[3];
    const float* W3 = (const float*)d_in[4];
    float* y = (float*)d_out;
    char* ws = (char*)d_ws;

    unsigned short* xb = (unsigned short*)(ws + OFF_XB);
    unsigned short* U  = (unsigned short*)(ws + OFF_U);
    float* Yp  = (float*)(ws + OFF_YP);
    int*   topi = (int*)(ws + OFF_TOPI);
    float* topw = (float*)(ws + OFF_TOPW);
    int*   tpos = (int*)(ws + OFF_TPOS);
    int*   ltok = (int*)(ws + OFF_LTOK);
    int*   meta = (int*)(ws + OFF_META);
    int* counts = meta;
    int* cursor = meta + 8;
    int* offs   = meta + 16;

    hipMemsetAsync(meta, 0, 64, stream);

    k_convert<<<T_TOK * D_DIM / (256 * 8), 256, 0, stream>>>(x, xb);
    k_gate<<<T_TOK / 4, 256, 0, stream>>>(x, Wg, topi, topw, counts);
    k_scan<<<1, 64, 0, stream>>>(counts, offs, cursor);
    k_scatter<<<T_TOK / 256, 256, 0, stream>>>(topi, cursor, ltok, tpos);
    k_gemm13<<<dim3(H_DIM / 16, E_NUM), 256, 0, stream>>>(xb, W1, W3, ltok, offs, counts, U);
    k_gemm2<<<dim3(D_DIM / 16, E_NUM), 256, 0, stream>>>(U, W2, offs, counts, Yp);
    k_combine<<<T_TOK * D_DIM / (256 * 4), 256, 0, stream>>>(Yp, tpos, topw, y);
}

// Round 4
// 499.258 us; speedup vs baseline: 1.4568x; 1.4568x over previous
//
#include <hip/hip_runtime.h>
#include <hip/hip_bf16.h>

#define T_TOK 2048
#define D_DIM 1024
#define H_DIM 2816
#define E_NUM 8
#define NPOS  (2 * T_TOK)      // 4096 pair-rows
#define SLACK 1024             // extra xg/U rows so staging never needs clamping

typedef __attribute__((ext_vector_type(8))) short short8;
typedef __attribute__((ext_vector_type(4))) float floatx4;

__device__ __forceinline__ unsigned short f2bf(float f) {
    unsigned int b = __float_as_uint(f);
    b += 0x7FFFu + ((b >> 16) & 1u);   // round-to-nearest-even
    return (unsigned short)(b >> 16);
}

__device__ __forceinline__ short8 pack8(float4 a, float4 b) {
    short8 o;
    o[0] = (short)f2bf(a.x); o[1] = (short)f2bf(a.y);
    o[2] = (short)f2bf(a.z); o[3] = (short)f2bf(a.w);
    o[4] = (short)f2bf(b.x); o[5] = (short)f2bf(b.y);
    o[6] = (short)f2bf(b.z); o[7] = (short)f2bf(b.w);
    return o;
}

// async 16B global->LDS. LDS dest = wave-uniform base + lane*16.
__device__ __forceinline__ void gl2lds16(const void* g, void* l) {
    __builtin_amdgcn_global_load_lds(
        (const __attribute__((address_space(1))) unsigned int*)g,
        (__attribute__((address_space(3))) unsigned int*)l,
        16, 0, 0);
}

// Swizzled LDS tile layout (rows of 64 bf16 = 8 chunks of 16B):
//   byte(row, slot) = (row>>3)*1056 + (row&7)*128 + slot*16
//   content(row, slot) = global chunk (slot ^ (row&7))
// gl2lds identity mapping lane L -> (row L>>3, slot L&7) with the XOR baked
// into the per-lane GLOBAL base gives exactly this layout; +32B pad per
// 8-row group rotates banks between groups.

// ---------------- gating: wave per token ----------------
__global__ __launch_bounds__(256) void k_gate(const float* __restrict__ x,
                                              const float* __restrict__ Wg,
                                              int* __restrict__ topi, float* __restrict__ topw,
                                              int* __restrict__ counts) {
    int wave = threadIdx.x >> 6, lane = threadIdx.x & 63;
    int t = blockIdx.x * 4 + wave;
    const float* xr = x + (size_t)t * D_DIM;
    float acc[E_NUM];
#pragma unroll
    for (int e = 0; e < E_NUM; ++e) acc[e] = 0.f;
    for (int i = 0; i < D_DIM / 64; ++i) {
        float xv = xr[lane + 64 * i];
#pragma unroll
        for (int e = 0; e < E_NUM; ++e) acc[e] += xv * Wg[e * D_DIM + lane + 64 * i];
    }
#pragma unroll
    for (int e = 0; e < E_NUM; ++e) {
#pragma unroll
        for (int s = 32; s > 0; s >>= 1) acc[e] += __shfl_xor(acc[e], s, 64);
    }
    if (lane == 0) {
        float mx = acc[0];
#pragma unroll
        for (int e = 1; e < E_NUM; ++e) mx = fmaxf(mx, acc[e]);
        float p[E_NUM], s = 0.f;
#pragma unroll
        for (int e = 0; e < E_NUM; ++e) { p[e] = expf(acc[e] - mx); s += p[e]; }
        int i0 = 0;
#pragma unroll
        for (int e = 1; e < E_NUM; ++e) if (p[e] > p[i0]) i0 = e;
        int i1 = (i0 == 0) ? 1 : 0;
#pragma unroll
        for (int e = 0; e < E_NUM; ++e) if (e != i0 && p[e] > p[i1]) i1 = e;
        float s0 = p[i0] / s, s1 = p[i1] / s;
        float d = s0 + s1 + 1e-20f;
        topi[t * 2] = i0; topi[t * 2 + 1] = i1;
        topw[t * 2] = s0 / d; topw[t * 2 + 1] = s1 / d;
        atomicAdd(&counts[i0], 1);
        atomicAdd(&counts[i1], 1);
    }
}

__global__ void k_scan(const int* __restrict__ counts, int* __restrict__ offs,
                       int* __restrict__ cursor) {
    if (threadIdx.x == 0) {
        int s = 0;
        for (int e = 0; e < E_NUM; ++e) { offs[e] = s; cursor[e] = s; s += counts[e]; }
        offs[E_NUM] = s;
    }
}

__global__ __launch_bounds__(256) void k_scatter(const int* __restrict__ topi,
                                                 int* __restrict__ cursor,
                                                 int* __restrict__ ltok,
                                                 int* __restrict__ tpos) {
    int t = blockIdx.x * 256 + threadIdx.x;
#pragma unroll
    for (int k = 0; k < 2; ++k) {
        int e = topi[t * 2 + k];
        int pos = atomicAdd(&cursor[e], 1);
        ltok[pos] = t;
        tpos[t * 2 + k] = pos;
    }
}

// ---- gather+convert: xg[pos][:] = bf16(x[ltok[pos]][:]) ----
__global__ __launch_bounds__(256) void k_gather(const float* __restrict__ x,
                                                const int* __restrict__ ltok,
                                                unsigned short* __restrict__ xg) {
    int p = blockIdx.x;
    int t = ltok[p];
    const float4* src = (const float4*)(x + (size_t)t * D_DIM);
    ushort4* dst = (ushort4*)(xg + (size_t)p * D_DIM);
    float4 v = src[threadIdx.x];
    ushort4 o;
    o.x = f2bf(v.x); o.y = f2bf(v.y); o.z = f2bf(v.z); o.w = f2bf(v.w);
    dst[threadIdx.x] = o;
}

// ---- GEMM 1&3: U = silu(xg W1^T) * (xg W3^T). BM=256, BN=32+32, BK=64 ----
__global__ __launch_bounds__(256) void k_gemm13(const unsigned short* __restrict__ xg,
                                                const float* __restrict__ W1,
                                                const float* __restrict__ W3,
                                                const int* __restrict__ offs,
                                                const int* __restrict__ counts,
                                                unsigned short* __restrict__ U) {
    const int nt = blockIdx.x;       // H/32 = 88
    const int mt = blockIdx.y;       // 4
    const int e  = blockIdx.z;
    const int cnt = counts[e];
    if (mt * 256 >= cnt) return;
    const int off = offs[e];

    __shared__ __align__(16) unsigned char As[32 * 1056];   // 256 rows x 64 bf16, swizzled
    __shared__ __align__(16) unsigned char B1s[4 * 1056];   // 32 rows
    __shared__ __align__(16) unsigned char B3s[4 * 1056];

    const int tid = threadIdx.x, lane = tid & 63, wave = tid >> 6;
    const int fr = lane & 15, quad = lane >> 4, f7 = fr & 7, f8 = fr >> 3;

    // A staging: wave w, call j stages rows [wave*64 + j*8, +8)
    const unsigned short* aBase = xg
        + ((size_t)off + mt * 256 + wave * 64 + (lane >> 3)) * D_DIM
        + ((lane & 7) ^ (lane >> 3)) * 8;

    // B staging: thread -> (row=tid>>3, chunk=tid&7), slot XOR-swizzled
    const int br = tid >> 3, bc = tid & 7;
    const float* w1p = W1 + ((size_t)e * H_DIM + nt * 32 + br) * D_DIM + bc * 8;
    const float* w3p = W3 + ((size_t)e * H_DIM + nt * 32 + br) * D_DIM + bc * 8;
    const int bslot = (br >> 3) * 1056 + (br & 7) * 128 + ((bc ^ (br & 7)) << 4);

    floatx4 acc1[4][2], acc3[4][2];
#pragma unroll
    for (int m = 0; m < 4; ++m)
#pragma unroll
        for (int n = 0; n < 2; ++n) { acc1[m][n] = (floatx4)0.f; acc3[m][n] = (floatx4)0.f; }

    const int agrp = (wave * 8 + f8) * 1056 + f7 * 128;
    const int c0 = (quad ^ f7) << 4;          // kk=0 chunk byte offset
    const int c1 = ((4 | quad) ^ f7) << 4;    // kk=1

#pragma unroll 1
    for (int k0 = 0; k0 < D_DIM; k0 += 64) {
#pragma unroll
        for (int j = 0; j < 8; ++j)
            gl2lds16(aBase + (size_t)j * 8 * D_DIM + k0, As + (wave * 8 + j) * 1056);
        float4 u0 = *(const float4*)(w1p + k0);
        float4 u1 = *(const float4*)(w1p + k0 + 4);
        float4 v0 = *(const float4*)(w3p + k0);
        float4 v1 = *(const float4*)(w3p + k0 + 4);
        *(short8*)(B1s + bslot) = pack8(u0, u1);
        *(short8*)(B3s + bslot) = pack8(v0, v1);
        __syncthreads();

        short8 b1f[2][2], b3f[2][2];
#pragma unroll
        for (int n = 0; n < 2; ++n) {
            const int bg = (n * 2 + f8) * 1056 + f7 * 128;
            b1f[n][0] = *(const short8*)(B1s + bg + c0);
            b1f[n][1] = *(const short8*)(B1s + bg + c1);
            b3f[n][0] = *(const short8*)(B3s + bg + c0);
            b3f[n][1] = *(const short8*)(B3s + bg + c1);
        }
#pragma unroll
        for (int m = 0; m < 4; ++m) {
            const unsigned char* ab = As + agrp + m * 2112;
            short8 a0 = *(const short8*)(ab + c0);
            short8 a1 = *(const short8*)(ab + c1);
#pragma unroll
            for (int n = 0; n < 2; ++n) {
                acc1[m][n] = __builtin_amdgcn_mfma_f32_16x16x32_bf16(a0, b1f[n][0], acc1[m][n], 0, 0, 0);
                acc1[m][n] = __builtin_amdgcn_mfma_f32_16x16x32_bf16(a1, b1f[n][1], acc1[m][n], 0, 0, 0);
                acc3[m][n] = __builtin_amdgcn_mfma_f32_16x16x32_bf16(a0, b3f[n][0], acc3[m][n], 0, 0, 0);
                acc3[m][n] = __builtin_amdgcn_mfma_f32_16x16x32_bf16(a1, b3f[n][1], acc3[m][n], 0, 0, 0);
            }
        }
        __syncthreads();
    }

#pragma unroll
    for (int m = 0; m < 4; ++m) {
#pragma unroll
        for (int r = 0; r < 4; ++r) {
            int g = mt * 256 + wave * 64 + m * 16 + quad * 4 + r;
            if (g < cnt) {
#pragma unroll
                for (int n = 0; n < 2; ++n) {
                    float u1v = acc1[m][n][r], u3v = acc3[m][n][r];
                    float u = u1v / (1.f + __expf(-u1v)) * u3v;
                    U[(size_t)(off + g) * H_DIM + nt * 32 + n * 16 + fr] = f2bf(u);
                }
            }
        }
    }
}

// ---- GEMM 2: Yp = U W2^T (unweighted). BM=256, BN=32, BK=64, K=2816 ----
__global__ __launch_bounds__(256) void k_gemm2(const unsigned short* __restrict__ U,
                                               const float* __restrict__ W2,
                                               const int* __restrict__ offs,
                                               const int* __restrict__ counts,
                                               float* __restrict__ Yp) {
    const int nt = blockIdx.x;       // D/32 = 32
    const int mt = blockIdx.y;       // 4
    const int e  = blockIdx.z;
    const int cnt = counts[e];
    if (mt * 256 >= cnt) return;
    const int off = offs[e];

    __shared__ __align__(16) unsigned char As[32 * 1056];
    __shared__ __align__(16) unsigned char Bs[4 * 1056];

    const int tid = threadIdx.x, lane = tid & 63, wave = tid >> 6;
    const int fr = lane & 15, quad = lane >> 4, f7 = fr & 7, f8 = fr >> 3;

    const unsigned short* aBase = U
        + ((size_t)off + mt * 256 + wave * 64 + (lane >> 3)) * H_DIM
        + ((lane & 7) ^ (lane >> 3)) * 8;

    const int br = tid >> 3, bc = tid & 7;
    const float* w2p = W2 + ((size_t)e * D_DIM + nt * 32 + br) * H_DIM + bc * 8;
    const int bslot = (br >> 3) * 1056 + (br & 7) * 128 + ((bc ^ (br & 7)) << 4);

    floatx4 acc[4][2];
#pragma unroll
    for (int m = 0; m < 4; ++m)
#pragma unroll
        for (int n = 0; n < 2; ++n) acc[m][n] = (floatx4)0.f;

    const int agrp = (wave * 8 + f8) * 1056 + f7 * 128;
    const int c0 = (quad ^ f7) << 4;
    const int c1 = ((4 | quad) ^ f7) << 4;

#pragma unroll 1
    for (int k0 = 0; k0 < H_DIM; k0 += 64) {
#pragma unroll
        for (int j = 0; j < 8; ++j)
            gl2lds16(aBase + (size_t)j * 8 * H_DIM + k0, As + (wave * 8 + j) * 1056);
        float4 u0 = *(const float4*)(w2p + k0);
        float4 u1 = *(const float4*)(w2p + k0 + 4);
        *(short8*)(Bs + bslot) = pack8(u0, u1);
        __syncthreads();

        short8 bf[2][2];
#pragma unroll
        for (int n = 0; n < 2; ++n) {
            const int bg = (n * 2 + f8) * 1056 + f7 * 128;
            bf[n][0] = *(const short8*)(Bs + bg + c0);
            bf[n][1] = *(const short8*)(Bs + bg + c1);
        }
#pragma unroll
        for (int m = 0; m < 4; ++m) {
            const unsigned char* ab = As + agrp + m * 2112;
            short8 a0 = *(const short8*)(ab + c0);
            short8 a1 = *(const short8*)(ab + c1);
#pragma unroll
            for (int n = 0; n < 2; ++n) {
                acc[m][n] = __builtin_amdgcn_mfma_f32_16x16x32_bf16(a0, bf[n][0], acc[m][n], 0, 0, 0);
                acc[m][n] = __builtin_amdgcn_mfma_f32_16x16x32_bf16(a1, bf[n][1], acc[m][n], 0, 0, 0);
            }
        }
        __syncthreads();
    }

#pragma unroll
    for (int m = 0; m < 4; ++m) {
#pragma unroll
        for (int r = 0; r < 4; ++r) {
            int g = mt * 256 + wave * 64 + m * 16 + quad * 4 + r;
            if (g < cnt) {
#pragma unroll
                for (int n = 0; n < 2; ++n)
                    Yp[(size_t)(off + g) * D_DIM + nt * 32 + n * 16 + fr] = acc[m][n][r];
            }
        }
    }
}

// ---- combine: y[t] = w0*Yp[p0] + w1*Yp[p1] ----
__global__ __launch_bounds__(256) void k_combine(const float* __restrict__ Yp,
                                                 const int* __restrict__ tpos,
                                                 const float* __restrict__ topw,
                                                 float* __restrict__ y) {
    int i = blockIdx.x * 256 + threadIdx.x;       // over T*D/4
    int t = i >> 8, c = i & 255;
    int p0 = tpos[t * 2], p1 = tpos[t * 2 + 1];
    float w0 = topw[t * 2], w1 = topw[t * 2 + 1];
    float4 a = ((const float4*)Yp)[(size_t)p0 * 256 + c];
    float4 b = ((const float4*)Yp)[(size_t)p1 * 256 + c];
    float4 o;
    o.x = w0 * a.x + w1 * b.x;
    o.y = w0 * a.y + w1 * b.y;
    o.z = w0 * a.z + w1 * b.z;
    o.w = w0 * a.w + w1 * b.w;
    ((float4*)y)[i] = o;
}

// ---------------- workspace layout ----------------
static const size_t OFF_XG   = 0;                                  // (NPOS+SLACK)*D*2  = 10,485,760
static const size_t OFF_U    = (size_t)(NPOS + SLACK) * D_DIM * 2; // (NPOS+SLACK)*H*2  = 28,835,840
static const size_t OFF_YP   = OFF_U + (size_t)(NPOS + SLACK) * H_DIM * 2;  // NPOS*D*4 = 16,777,216
static const size_t OFF_TOPI = OFF_YP + (size_t)NPOS * D_DIM * 4;
static const size_t OFF_TOPW = OFF_TOPI + 16384;
static const size_t OFF_TPOS = OFF_TOPW + 16384;
static const size_t OFF_LTOK = OFF_TPOS + 16384;
static const size_t OFF_META = OFF_LTOK + 16384;

extern "C" void kernel_launch(void* const* d_in, const int* in_sizes, int n_in,
                              void* d_out, int out_size, void* d_ws, size_t ws_size,
                              hipStream_t stream) {
    const float* x  = (const float*)d_in[0];
    const float* Wg = (const float*)d_in[1];
    const float* W1 = (const float*)d_in[2];
    const float* W2 = (const float*)d_in[3];
    const float* W3 = (const float*)d_in[4];
    float* y = (float*)d_out;
    char* ws = (char*)d_ws;

    unsigned short* xg = (unsigned short*)(ws + OFF_XG);
    unsigned short* U  = (unsigned short*)(ws + OFF_U);
    float* Yp   = (float*)(ws + OFF_YP);
    int*   topi = (int*)(ws + OFF_TOPI);
    float* topw = (float*)(ws + OFF_TOPW);
    int*   tpos = (int*)(ws + OFF_TPOS);
    int*   ltok = (int*)(ws + OFF_LTOK);
    int*   meta = (int*)(ws + OFF_META);
    int* counts = meta;
    int* cursor = meta + 8;
    int* offs   = meta + 16;

    hipMemsetAsync(meta, 0, 64, stream);

    k_gate<<<T_TOK / 4, 256, 0, stream>>>(x, Wg, topi, topw, counts);
    k_scan<<<1, 64, 0, stream>>>(counts, offs, cursor);
    k_scatter<<<T_TOK / 256, 256, 0, stream>>>(topi, cursor, ltok, tpos);
    k_gather<<<NPOS, 256, 0, stream>>>(x, ltok, xg);
    k_gemm13<<<dim3(H_DIM / 32, 4, E_NUM), 256, 0, stream>>>(xg, W1, W3, offs, counts, U);
    k_gemm2<<<dim3(D_DIM / 32, 4, E_NUM), 256, 0, stream>>>(U, W2, offs, counts, Yp);
    k_combine<<<T_TOK * D_DIM / (256 * 4), 256, 0, stream>>>(Yp, tpos, topw, y);
}